// Round 7
// baseline (104.853 us; speedup 1.0000x reference)
//
#include <hip/hip_runtime.h>
#include <hip/hip_bf16.h>

// Polyphase resampler, up=2/down=3, 128-tap FIR, via bf16 MFMA.
// R7 = DIAGNOSTIC round: exact R6 structure, but 8 rotated passes per block
// so the kernel dispatch (not harness fillBuffers) tops the rocprof table
// and exposes VALUBusy/MfmaUtil/Occupancy/LDS-conflict/VGPR for this code.
// All passes write identical correct values -> output correct & deterministic.
//   out[2g]   = 2 * sum_u W_g[u]   * fe_r[u],  W_g[k]=x[3g-32+k]
//   out[2g+1] = 2 * sum_u W_g[u+2] * fo_r[u]
// MFMA 16x16x32 bf16, K=96; D[i][j] = out[2g0+16i+j].

typedef __bf16 bf16x8 __attribute__((ext_vector_type(8)));
typedef float  f32x4  __attribute__((ext_vector_type(4)));

constexpr int BT     = 256;            // 4 waves
constexpr int GPB    = 2048;           // output pairs (g) per block-tile
constexpr int UPW    = GPB / 128 / 4;  // 128-pair MFMA units per wave (= 4)
constexpr int XT     = 3 * GPB + 96;   // 6240 staged bf16 x-elements
constexpr int XT4    = XT / 4;         // 1560 float4 groups
constexpr int PASSES = 8;              // diagnostic amplification
constexpr int ROT    = 911;            // tile rotation per pass

__global__ __launch_bounds__(BT) void resample23_mfma(
    const float* __restrict__ x,
    const float* __restrict__ filt,
    float* __restrict__ out,
    int N, int out_size)
{
    __shared__ __align__(16) unsigned short xs[XT];   // bf16 x tile (12480 B)

    const int t = threadIdx.x;
    const int w = t >> 6;
    const int l = t & 63;
    const int j = l & 15;
    const int nb = gridDim.x;

    for (int p = 0; p < PASSES; ++p) {
        int tid = blockIdx.x + p * ROT;
        tid -= (tid / nb) * nb;                       // tid mod nb
        const int G0 = tid * GPB;
        const long F0 = 3L * G0 - 32;                 // global float idx of xs[0]

        // opaque zero: defeats cross-pass CSE of the B-build filter loads
        int z = 0; asm volatile("" : "+v"(z));
        const float* fp = filt + z;

        // ---- stage x tile: f32 global -> bf16 LDS (coalesced float4) ----
        const bool interior = (F0 >= 0) && (F0 + XT <= (long)N);
        #pragma unroll
        for (int r = 0; r < (XT4 + BT - 1) / BT; ++r) {
            int idx = t + BT * r;
            if (idx < XT4) {
                long f0 = F0 + 4L * idx;
                float4 v;
                if (interior) {
                    v = *reinterpret_cast<const float4*>(x + f0);
                } else {
                    v.x = (f0 + 0 >= 0 && f0 + 0 < N) ? x[f0 + 0] : 0.0f;
                    v.y = (f0 + 1 >= 0 && f0 + 1 < N) ? x[f0 + 1] : 0.0f;
                    v.z = (f0 + 2 >= 0 && f0 + 2 < N) ? x[f0 + 2] : 0.0f;
                    v.w = (f0 + 3 >= 0 && f0 + 3 < N) ? x[f0 + 3] : 0.0f;
                }
                __hip_bfloat162 p0 = __float22bfloat162_rn(make_float2(v.x, v.y));
                __hip_bfloat162 p1 = __float22bfloat162_rn(make_float2(v.z, v.w));
                *reinterpret_cast<__hip_bfloat162*>(&xs[4 * idx + 0]) = p0;
                *reinterpret_cast<__hip_bfloat162*>(&xs[4 * idx + 2]) = p1;
            }
        }

        // ---- build B fragments (inline, overlaps staging latency) ----
        const int kq  = (l >> 4) * 8;
        const int dlt = j >> 1;
        const int ph  = j & 1;
        bf16x8 Bf[3];
        #pragma unroll
        for (int kc = 0; kc < 3; ++kc) {
            #pragma unroll
            for (int e = 0; e < 8; ++e) {
                int k = 32 * kc + kq + e;
                int v = k - 3 * dlt - 2 * ph;          // tap index u
                float fv = (v >= 0 && v < 64) ? fp[(ph ? 126 : 127) - 2 * v] : 0.0f;
                Bf[kc][e] = (__bf16)fv;
            }
        }

        __syncthreads();

        // ---- MFMA-triples: 256 contiguous outputs each ----
        const char* xsb = reinterpret_cast<const char*>(xs);
        #pragma unroll
        for (int s = 0; s < UPW; ++s) {
            const int u    = UPW * w + s;              // 128-pair unit
            const int g0   = G0 + 128 * u;
            const int boff = 768 * u + 48 * j + 16 * (l >> 4);

            f32x4 acc = {0.0f, 0.0f, 0.0f, 0.0f};
            bf16x8 a0 = *reinterpret_cast<const bf16x8*>(xsb + boff + 0);
            bf16x8 a1 = *reinterpret_cast<const bf16x8*>(xsb + boff + 64);
            bf16x8 a2 = *reinterpret_cast<const bf16x8*>(xsb + boff + 128);
            acc = __builtin_amdgcn_mfma_f32_16x16x32_bf16(a0, Bf[0], acc, 0, 0, 0);
            acc = __builtin_amdgcn_mfma_f32_16x16x32_bf16(a1, Bf[1], acc, 0, 0, 0);
            acc = __builtin_amdgcn_mfma_f32_16x16x32_bf16(a2, Bf[2], acc, 0, 0, 0);

            // D[i][j]: col=j, row=4*(l>>4)+r  ->  out[2*g0 + 16*row + col]
            const int obase = 2 * g0 + 64 * (l >> 4) + j;
            #pragma unroll
            for (int r = 0; r < 4; ++r) {
                int o = obase + 16 * r;
                if (o < out_size) out[o] = 2.0f * acc[r];
            }
        }

        __syncthreads();   // xs reused next pass
    }
}

extern "C" void kernel_launch(void* const* d_in, const int* in_sizes, int n_in,
                              void* d_out, int out_size, void* d_ws, size_t ws_size,
                              hipStream_t stream)
{
    const float* x    = (const float*)d_in[0];
    const float* filt = (const float*)d_in[1];
    float* out        = (float*)d_out;
    const int N       = in_sizes[0];

    const int n_pairs = (out_size + 1) / 2;
    const int blocks  = (n_pairs + GPB - 1) / GPB;
    resample23_mfma<<<blocks, BT, 0, stream>>>(x, filt, out, N, out_size);
}

// Round 9
// 24.484 us; speedup vs baseline: 4.2826x; 4.2826x over previous
//
#include <hip/hip_runtime.h>
#include <hip/hip_bf16.h>

// Polyphase resampler, up=2/down=3, 128-tap FIR, via bf16 MFMA.
//   out[2g]   = 2 * sum_u W_g[u]   * fe_r[u],  W_g[k]=x[3g-32+k]
//   out[2g+1] = 2 * sum_u W_g[u+2] * fo_r[u]
// MFMA 16x16x32 bf16, K=96; D[i][j] = out[2g0+16i+j].
//
// R9: R8's barrier-free counted-vmcnt pipeline, with WAVE-PRIVATE LDS
// slices (xs[2][4][512]). R8 raced: adjacent waves shared a 72-f32 overlap
// of the staged tile with no barrier. Now each wave stages+reads only its
// own 512-f32 slice (reads reach +455 < 512) -> zero cross-wave coupling.

typedef __bf16 bf16x8 __attribute__((ext_vector_type(8)));
typedef float  f32x4  __attribute__((ext_vector_type(4)));

constexpr int BT    = 256;     // 4 waves
constexpr int GPB   = 512;     // output pairs per tile (1 MFMA unit per wave)
constexpr int TPB   = 4;       // tiles per block (unrolled pipeline)
constexpr int WSL   = 512;     // wave-private slice (f32) per tile buffer
constexpr int XSPAN = 1664;    // global f32 span touched per tile (bound check)

__device__ __forceinline__ void gload_lds16(const float* g, float* l) {
    __builtin_amdgcn_global_load_lds(
        (const __attribute__((address_space(1))) void*)g,
        (__attribute__((address_space(3))) void*)l, 16, 0, 0);
}

__device__ __forceinline__ bf16x8 cvt8(float4 a, float4 b) {
    union { bf16x8 v; __hip_bfloat162 h[4]; } u;
    u.h[0] = __float22bfloat162_rn(make_float2(a.x, a.y));
    u.h[1] = __float22bfloat162_rn(make_float2(a.z, a.w));
    u.h[2] = __float22bfloat162_rn(make_float2(b.x, b.y));
    u.h[3] = __float22bfloat162_rn(make_float2(b.z, b.w));
    return u.v;
}

__global__ __launch_bounds__(BT) void resample23_mfma(
    const float* __restrict__ x,
    const float* __restrict__ filt,
    float* __restrict__ out,
    int N, int out_size, int n_tiles)
{
    __shared__ __align__(16) float xs[2][4][WSL];   // 16384 B, wave-private slices

    const int t = threadIdx.x;
    const int w = t >> 6, l = t & 63;
    const int j = l & 15, q = l >> 4;

    // ---- B fragments (once per wave; amortized over TPB tiles) ----
    const int kq = q * 8, dlt = j >> 1, ph = j & 1;
    bf16x8 Bf[3];
    #pragma unroll
    for (int kc = 0; kc < 3; ++kc) {
        #pragma unroll
        for (int e = 0; e < 8; ++e) {
            int k = 32 * kc + kq + e;
            int v = k - 3 * dlt - 2 * ph;          // tap index u
            float fv = (v >= 0 && v < 64) ? filt[(ph ? 126 : 127) - 2 * v] : 0.0f;
            Bf[kc][e] = (__bf16)fv;
        }
    }

    const int t0 = blockIdx.x * TPB;
    const int te = (t0 + TPB < n_tiles) ? t0 + TPB : n_tiles;
    const int rb = 24 * j + 8 * q;     // per-lane A-read base within wave slice

    // per-tile: ds_read A (f32) from own slice, cvt->bf16, 3 MFMA, 4 stores
    auto compute = [&](int tt, const float* wavebuf) {
        const float* bp = wavebuf + rb;
        bf16x8 A0 = cvt8(*(const float4*)(bp +  0), *(const float4*)(bp +  4));
        bf16x8 A1 = cvt8(*(const float4*)(bp + 32), *(const float4*)(bp + 36));
        bf16x8 A2 = cvt8(*(const float4*)(bp + 64), *(const float4*)(bp + 68));
        f32x4 acc = {0.0f, 0.0f, 0.0f, 0.0f};
        acc = __builtin_amdgcn_mfma_f32_16x16x32_bf16(A0, Bf[0], acc, 0, 0, 0);
        acc = __builtin_amdgcn_mfma_f32_16x16x32_bf16(A1, Bf[1], acc, 0, 0, 0);
        acc = __builtin_amdgcn_mfma_f32_16x16x32_bf16(A2, Bf[2], acc, 0, 0, 0);
        const int obase = 2 * (tt * GPB + 128 * w) + 64 * q + j;
        #pragma unroll
        for (int r = 0; r < 4; ++r) {
            int o = obase + 16 * r;
            if (o < out_size) out[o] = 2.0f * acc[r];
        }
    };

    // wave w stages x[F0+384w .. F0+384w+512) into ITS OWN slice
    auto stage_fast = [&](int tt, float* wavebuf) {
        const float* src = x + (3L * tt * GPB - 32) + 384 * w + 4 * l;
        float* dst = wavebuf + 4 * l;
        gload_lds16(src, dst);
        gload_lds16(src + 256, dst + 256);
    };

    const long lastF0 = 3L * (t0 + TPB - 1) * GPB - 32;
    const bool fast = (t0 > 0) && (te == t0 + TPB) && (lastF0 + XSPAN <= (long)N);

    if (fast) {
        stage_fast(t0 + 0, xs[0][w]);
        stage_fast(t0 + 1, xs[1][w]);
        // loads(t0) done: exactly 2 ops (loads t1) issued after them
        asm volatile("s_waitcnt vmcnt(2)" ::: "memory");
        compute(t0 + 0, xs[0][w]);
        asm volatile("s_waitcnt lgkmcnt(0)" ::: "memory");  // WAR: buf0 reads landed
        stage_fast(t0 + 2, xs[0][w]);
        // outstanding: 2L(t1)+4S(t0)+2L(t2)=8 -> wait to 6 completes L(t1)
        asm volatile("s_waitcnt vmcnt(6)" ::: "memory");
        compute(t0 + 1, xs[1][w]);
        asm volatile("s_waitcnt lgkmcnt(0)" ::: "memory");
        stage_fast(t0 + 3, xs[1][w]);
        // outstanding: 4S(t0)+2L(t2)+4S(t1)+2L(t3)=12 -> 6 completes thru L(t2)
        asm volatile("s_waitcnt vmcnt(6)" ::: "memory");
        compute(t0 + 2, xs[0][w]);
        // outstanding: 4S(t1)+2L(t3)+4S(t2)=10 -> 4 completes thru L(t3)
        asm volatile("s_waitcnt vmcnt(4)" ::: "memory");
        compute(t0 + 3, xs[1][w]);
    } else {
        // boundary blocks (first / last): serial guarded staging, wave-private
        for (int tt = t0; tt < te; ++tt) {
            float* wavebuf = xs[tt & 1][w];
            const long F0 = 3L * tt * GPB - 32 + 384 * w;
            #pragma unroll
            for (int k = 0; k < 8; ++k) {
                long gi = F0 + 64 * k + l;
                wavebuf[64 * k + l] = (gi >= 0 && gi < (long)N) ? x[gi] : 0.0f;
            }
            __builtin_amdgcn_s_waitcnt(0);   // ds_writes visible before reads
            compute(tt, wavebuf);
        }
    }
}

extern "C" void kernel_launch(void* const* d_in, const int* in_sizes, int n_in,
                              void* d_out, int out_size, void* d_ws, size_t ws_size,
                              hipStream_t stream)
{
    const float* x    = (const float*)d_in[0];
    const float* filt = (const float*)d_in[1];
    float* out        = (float*)d_out;
    const int N       = in_sizes[0];

    const int n_pairs = (out_size + 1) / 2;
    const int n_tiles = (n_pairs + GPB - 1) / GPB;
    const int blocks  = (n_tiles + TPB - 1) / TPB;
    resample23_mfma<<<blocks, BT, 0, stream>>>(x, filt, out, N, out_size, n_tiles);
}